// Round 1
// baseline (506.234 us; speedup 1.0000x reference)
//
#include <hip/hip_runtime.h>
#include <hip/hip_bf16.h>

#define K_DIM 4096
#define N_DIM 12288
#define B_DIM 64
#define G_DIM 64          // K / 64 groups
#define R_DIM 32

typedef int v4i __attribute__((ext_vector_type(4)));

// ---------------------------------------------------------------------------
// Kernel 1: smoothing divide + per-(token,group) int4 symmetric quantization.
// One block per token b; 4 waves x 16 groups; one wave lane per k in a group.
// Bit-exact vs reference: IEEE fp32 div, rintf == jnp.round (half-to-even).
// ---------------------------------------------------------------------------
__global__ __launch_bounds__(256) void quant_kernel(
    const float* __restrict__ x, const float* __restrict__ smooth,
    char* __restrict__ xq, float* __restrict__ ascale) {
    const int b = blockIdx.x;
    const int w = threadIdx.x >> 6, lane = threadIdx.x & 63;
    for (int gi = 0; gi < 16; ++gi) {
        const int g = w * 16 + gi;
        const int k = g * 64 + lane;
        const float xd = x[b * K_DIM + k] / smooth[k];
        float a = fabsf(xd);
        #pragma unroll
        for (int off = 32; off; off >>= 1) a = fmaxf(a, __shfl_xor(a, off));
        const float as = fmaxf(a / 7.0f, 1e-8f);
        float q = rintf(xd / as);
        q = fminf(fmaxf(q, -8.0f), 7.0f);
        xq[b * K_DIM + k] = (char)(int)q;
        if (lane == 0) ascale[b * G_DIM + g] = as;
    }
}

// ---------------------------------------------------------------------------
// Kernel 2: t[b, r] = sum_k (x[b,k]/smooth[k]) * lora_down[k, r].  [64 x 32]
// One block per token; thread (r = t&31, chunk = t>>5) -> LDS reduce.
// ---------------------------------------------------------------------------
__global__ __launch_bounds__(256) void lora_down_kernel(
    const float* __restrict__ x, const float* __restrict__ smooth,
    const float* __restrict__ ld, float* __restrict__ t) {
    const int b = blockIdx.x;
    const int r = threadIdx.x & 31;
    const int c = threadIdx.x >> 5;   // 0..7
    float acc = 0.f;
    const int k0 = c * (K_DIM / 8);
    for (int k = k0; k < k0 + K_DIM / 8; ++k) {
        const float xd = x[b * K_DIM + k] / smooth[k];
        acc += xd * ld[k * R_DIM + r];
    }
    __shared__ float red[256];
    red[threadIdx.x] = acc;
    __syncthreads();
    if (threadIdx.x < 32) {
        float s = 0.f;
        #pragma unroll
        for (int c2 = 0; c2 < 8; ++c2) s += red[c2 * 32 + threadIdx.x];
        t[b * R_DIM + threadIdx.x] = s;
    }
}

// ---------------------------------------------------------------------------
// Kernel 3: main W4A4 GEMM via mfma_i32_16x16x64_i8 (K per MFMA == group=64)
//   y[b,n] = sum_g ascale[b,g]*wscale[g,n]*(int dot) + t[b,:]@lora_up[n,:] + bias[n]
// Grid: 768 blocks = one per 16-wide n tile. 4 waves, wave w covers groups
// [16w, 16w+16). Each wave holds all 4 b-tiles so q_w is read exactly once.
// ---------------------------------------------------------------------------
__global__ __launch_bounds__(256) void main_kernel(
    const int* __restrict__ qw, const float* __restrict__ wscales,
    const char* __restrict__ xq, const float* __restrict__ ascale,
    const float* __restrict__ t, const float* __restrict__ lora_up,
    const float* __restrict__ bias, float* __restrict__ out) {
    __shared__ float s_ws[G_DIM * 16];        // wscales[g][n0+j]      4 KB
    __shared__ float s_as[B_DIM * G_DIM];     // ascale[b][g]         16 KB
    __shared__ float s_red[4 * 64 * 16];      // cross-wave reduce    16 KB

    const int n0 = blockIdx.x * 16;
    const int tid = threadIdx.x;

    for (int i = tid; i < G_DIM * 16; i += 256) {
        const int g = i >> 4, j = i & 15;
        s_ws[i] = wscales[g * N_DIM + n0 + j];
    }
    for (int i = tid; i < B_DIM * G_DIM; i += 256) s_as[i] = ascale[i];
    __syncthreads();

    const int w = tid >> 6, lane = tid & 63;
    const int col = lane & 15, quad = lane >> 4;

    float facc[4][4];
    #pragma unroll
    for (int bt = 0; bt < 4; ++bt)
        #pragma unroll
        for (int r = 0; r < 4; ++r) facc[bt][r] = 0.f;

    const int krow = quad * 16;               // this lane's k offset in group
    const v4i zero = {0, 0, 0, 0};

    for (int gi = 0; gi < 16; ++gi) {
        const int g = w * 16 + gi;
        const int kbase = g * 64 + krow;
        // ---- B fragment: q_w row n = n0+col, 16 int32 -> 16 packed int8 ----
        const int* qptr = qw + (size_t)(n0 + col) * K_DIM + kbase;
        const v4i q0 = *(const v4i*)(qptr);
        const v4i q1 = *(const v4i*)(qptr + 4);
        const v4i q2 = *(const v4i*)(qptr + 8);
        const v4i q3 = *(const v4i*)(qptr + 12);
        v4i bfrag;
        bfrag.x = (q0.x & 255) | ((q0.y & 255) << 8) | ((q0.z & 255) << 16) | (q0.w << 24);
        bfrag.y = (q1.x & 255) | ((q1.y & 255) << 8) | ((q1.z & 255) << 16) | (q1.w << 24);
        bfrag.z = (q2.x & 255) | ((q2.y & 255) << 8) | ((q2.z & 255) << 16) | (q2.w << 24);
        bfrag.w = (q3.x & 255) | ((q3.y & 255) << 8) | ((q3.z & 255) << 16) | (q3.w << 24);
        const float wsc = s_ws[g * 16 + col];
        #pragma unroll
        for (int bt = 0; bt < 4; ++bt) {
            const char* aptr = xq + (size_t)(bt * 16 + col) * K_DIM + kbase;
            const v4i afrag = *(const v4i*)aptr;
            const v4i d = __builtin_amdgcn_mfma_i32_16x16x64_i8(afrag, bfrag, zero, 0, 0, 0);
            #pragma unroll
            for (int r = 0; r < 4; ++r) {
                const int b = bt * 16 + quad * 4 + r;
                facc[bt][r] += s_as[b * G_DIM + g] * wsc * (float)d[r];
            }
        }
    }

    // ---- cross-wave reduction + epilogue ----
    #pragma unroll
    for (int bt = 0; bt < 4; ++bt)
        #pragma unroll
        for (int r = 0; r < 4; ++r)
            s_red[w * 1024 + lane * 16 + bt * 4 + r] = facc[bt][r];
    __syncthreads();

    #pragma unroll
    for (int i = 0; i < 4; ++i) {
        const int o = tid + i * 256;          // 0..1023, conflict-free reads
        const float v = s_red[o] + s_red[1024 + o] + s_red[2048 + o] + s_red[3072 + o];
        const int lane_o = o >> 4;
        const int bt = (o >> 2) & 3, r = o & 3;
        const int b = bt * 16 + (lane_o >> 4) * 4 + r;
        const int n = n0 + (lane_o & 15);
        float acc = v + bias[n];
        const float* tp = t + b * R_DIM;
        const float* lp = lora_up + (size_t)n * R_DIM;
        #pragma unroll
        for (int r2 = 0; r2 < R_DIM; ++r2) acc += tp[r2] * lp[r2];
        out[(size_t)b * N_DIM + n] = acc;
    }
}

// ---------------------------------------------------------------------------
extern "C" void kernel_launch(void* const* d_in, const int* in_sizes, int n_in,
                              void* d_out, int out_size, void* d_ws, size_t ws_size,
                              hipStream_t stream) {
    const float* x         = (const float*)d_in[0];
    const int*   q_w       = (const int*)d_in[1];
    const float* wscales   = (const float*)d_in[2];
    const float* lora_down = (const float*)d_in[3];
    const float* lora_up   = (const float*)d_in[4];
    const float* smooth    = (const float*)d_in[5];
    const float* bias      = (const float*)d_in[6];
    float* out = (float*)d_out;

    char*  xq     = (char*)d_ws;                         // 256 KB
    float* ascale = (float*)((char*)d_ws + 262144);      // 16 KB
    float* t      = (float*)((char*)d_ws + 262144 + 16384); // 8 KB

    quant_kernel<<<B_DIM, 256, 0, stream>>>(x, smooth, xq, ascale);
    lora_down_kernel<<<B_DIM, 256, 0, stream>>>(x, smooth, lora_down, t);
    main_kernel<<<N_DIM / 16, 256, 0, stream>>>(q_w, wscales, xq, ascale,
                                                t, lora_up, bias, out);
}

// Round 2
// 340.516 us; speedup vs baseline: 1.4867x; 1.4867x over previous
//
#include <hip/hip_runtime.h>
#include <hip/hip_bf16.h>

#define K_DIM 4096
#define N_DIM 12288
#define B_DIM 64
#define G_DIM 64          // K / 64 groups
#define R_DIM 32
#define AS_LD 68          // padded leading dim for s_as[g][b]

typedef int v4i __attribute__((ext_vector_type(4)));

// ---------------------------------------------------------------------------
// Kernel 1: smoothing divide + per-(token,group) int4 symmetric quantization.
// Grid = B*G/4 = 1024 blocks; 4 waves/block, one wave per group, one lane per k.
// Bit-exact vs reference: IEEE fp32 div, rintf == jnp.round (half-to-even).
// ---------------------------------------------------------------------------
__global__ __launch_bounds__(256) void quant_kernel(
    const float* __restrict__ x, const float* __restrict__ smooth,
    char* __restrict__ xq, float* __restrict__ ascale) {
    const int b = blockIdx.x >> 4;
    const int gq = blockIdx.x & 15;
    const int w = threadIdx.x >> 6, lane = threadIdx.x & 63;
    const int g = gq * 4 + w;
    const int k = g * 64 + lane;
    const float xd = x[b * K_DIM + k] / smooth[k];
    float a = fabsf(xd);
    #pragma unroll
    for (int off = 32; off; off >>= 1) a = fmaxf(a, __shfl_xor(a, off));
    const float as = fmaxf(a / 7.0f, 1e-8f);
    float q = rintf(xd / as);
    q = fminf(fmaxf(q, -8.0f), 7.0f);
    xq[b * K_DIM + k] = (char)(int)q;
    if (lane == 0) ascale[b * G_DIM + g] = as;
}

// ---------------------------------------------------------------------------
// Kernel 2: t[b, r] += sum_{k in chunk} (x[b,k]/smooth[k]) * lora_down[k, r].
// Grid = 64 tokens x 16 k-chunks = 1024 blocks. Each thread: r = tid&31,
// sub-chunk c = tid>>5 (32 k each). LDS reduce 8->1, one atomicAdd per (b,r).
// t must be zeroed before launch (hipMemsetAsync).
// ---------------------------------------------------------------------------
__global__ __launch_bounds__(256) void lora_down_kernel(
    const float* __restrict__ x, const float* __restrict__ smooth,
    const float* __restrict__ ld, float* __restrict__ t) {
    const int b = blockIdx.x >> 4;
    const int kc = blockIdx.x & 15;
    const int r = threadIdx.x & 31;
    const int c = threadIdx.x >> 5;   // 0..7
    const int k0 = kc * 256 + c * 32;
    float acc = 0.f;
    #pragma unroll 8
    for (int k = k0; k < k0 + 32; ++k) {
        const float xd = x[b * K_DIM + k] / smooth[k];
        acc += xd * ld[k * R_DIM + r];
    }
    __shared__ float red[256];
    red[threadIdx.x] = acc;
    __syncthreads();
    if (threadIdx.x < 32) {
        float s = 0.f;
        #pragma unroll
        for (int c2 = 0; c2 < 8; ++c2) s += red[c2 * 32 + threadIdx.x];
        atomicAdd(&t[b * R_DIM + threadIdx.x], s);
    }
}

// ---------------------------------------------------------------------------
// Kernel 3: main W4A4 GEMM via mfma_i32_16x16x64_i8 (K per MFMA == group=64)
//   y[b,n] = sum_g ascale[b,g]*wscale[g,n]*(int dot) + t[b,:]@lora_up[n,:] + bias[n]
// Grid: 768 blocks = one per 16-wide n tile. 4 waves, wave w covers groups
// [16w, 16w+16). Software-pipelined: q_w + xq for group gi+1 prefetched while
// computing group gi, so each wave keeps ~5 KB of loads in flight.
// ---------------------------------------------------------------------------
__global__ __launch_bounds__(256) void main_kernel(
    const int* __restrict__ qw, const float* __restrict__ wscales,
    const char* __restrict__ xq, const float* __restrict__ ascale,
    const float* __restrict__ t, const float* __restrict__ lora_up,
    const float* __restrict__ bias, float* __restrict__ out) {
    __shared__ float s_ws[G_DIM * 16];        // wscales[g][n0+j]        4 KB
    __shared__ float s_as[G_DIM * AS_LD];     // ascale transposed [g][b] 17 KB
    __shared__ float s_red[4 * 64 * 16];      // cross-wave reduce       16 KB

    const int n0 = blockIdx.x * 16;
    const int tid = threadIdx.x;

    for (int i = tid; i < G_DIM * 16; i += 256) {
        const int g = i >> 4, j = i & 15;
        s_ws[i] = wscales[g * N_DIM + n0 + j];
    }
    for (int i = tid; i < B_DIM * G_DIM; i += 256) {
        const int b = i >> 6, g = i & 63;      // coalesced global read
        s_as[g * AS_LD + b] = ascale[i];       // 8-way LDS write conflict, one-time
    }
    __syncthreads();

    const int w = tid >> 6, lane = tid & 63;
    const int col = lane & 15, quad = lane >> 4;
    const int g0 = w * 16;

    float facc[4][4];
    #pragma unroll
    for (int bt = 0; bt < 4; ++bt)
        #pragma unroll
        for (int r = 0; r < 4; ++r) facc[bt][r] = 0.f;

    const v4i zero = {0, 0, 0, 0};
    const int* qbase = qw + (size_t)(n0 + col) * K_DIM + quad * 16;
    const char* xbase = xq + (size_t)col * K_DIM + quad * 16;

    v4i q[4], xa[4];
    {   // prefetch group g0
        const int* p = qbase + g0 * 64;
        q[0] = *(const v4i*)(p);
        q[1] = *(const v4i*)(p + 4);
        q[2] = *(const v4i*)(p + 8);
        q[3] = *(const v4i*)(p + 12);
        #pragma unroll
        for (int bt = 0; bt < 4; ++bt)
            xa[bt] = *(const v4i*)(xbase + (size_t)(bt * 16) * K_DIM + g0 * 64);
    }

    for (int gi = 0; gi < 16; ++gi) {
        const int g = g0 + gi;
        // ---- prefetch group gi+1 (last iter: re-touch current group, L1-hot)
        const int gn = g0 + (gi < 15 ? gi + 1 : gi);
        v4i qn[4], xan[4];
        {
            const int* p = qbase + gn * 64;
            qn[0] = *(const v4i*)(p);
            qn[1] = *(const v4i*)(p + 4);
            qn[2] = *(const v4i*)(p + 8);
            qn[3] = *(const v4i*)(p + 12);
            #pragma unroll
            for (int bt = 0; bt < 4; ++bt)
                xan[bt] = *(const v4i*)(xbase + (size_t)(bt * 16) * K_DIM + gn * 64);
        }
        // ---- pack current q_w 16 int32 -> 16 packed int8 ----
        v4i bfrag;
        bfrag.x = (q[0].x & 255) | ((q[0].y & 255) << 8) | ((q[0].z & 255) << 16) | (q[0].w << 24);
        bfrag.y = (q[1].x & 255) | ((q[1].y & 255) << 8) | ((q[1].z & 255) << 16) | (q[1].w << 24);
        bfrag.z = (q[2].x & 255) | ((q[2].y & 255) << 8) | ((q[2].z & 255) << 16) | (q[2].w << 24);
        bfrag.w = (q[3].x & 255) | ((q[3].y & 255) << 8) | ((q[3].z & 255) << 16) | (q[3].w << 24);
        const float wsc = s_ws[g * 16 + col];
        #pragma unroll
        for (int bt = 0; bt < 4; ++bt) {
            const v4i d = __builtin_amdgcn_mfma_i32_16x16x64_i8(xa[bt], bfrag, zero, 0, 0, 0);
            const float4 as4 = *(const float4*)&s_as[g * AS_LD + bt * 16 + quad * 4];
            facc[bt][0] = fmaf(as4.x * wsc, (float)d[0], facc[bt][0]);
            facc[bt][1] = fmaf(as4.y * wsc, (float)d[1], facc[bt][1]);
            facc[bt][2] = fmaf(as4.z * wsc, (float)d[2], facc[bt][2]);
            facc[bt][3] = fmaf(as4.w * wsc, (float)d[3], facc[bt][3]);
        }
        #pragma unroll
        for (int j = 0; j < 4; ++j) { q[j] = qn[j]; xa[j] = xan[j]; }
    }

    // ---- cross-wave reduction + epilogue ----
    #pragma unroll
    for (int bt = 0; bt < 4; ++bt)
        #pragma unroll
        for (int r = 0; r < 4; ++r)
            s_red[w * 1024 + lane * 16 + bt * 4 + r] = facc[bt][r];
    __syncthreads();

    #pragma unroll
    for (int i = 0; i < 4; ++i) {
        const int o = tid + i * 256;          // 0..1023, conflict-free reads
        const float v = s_red[o] + s_red[1024 + o] + s_red[2048 + o] + s_red[3072 + o];
        const int lane_o = o >> 4;
        const int bt = (o >> 2) & 3, r = o & 3;
        const int b = bt * 16 + (lane_o >> 4) * 4 + r;
        const int n = n0 + (lane_o & 15);
        float acc = v + bias[n];
        const float4* tp = (const float4*)(t + b * R_DIM);
        const float4* lp = (const float4*)(lora_up + (size_t)n * R_DIM);
        #pragma unroll
        for (int r2 = 0; r2 < R_DIM / 4; ++r2) {
            const float4 tv = tp[r2], lv = lp[r2];
            acc += tv.x * lv.x + tv.y * lv.y + tv.z * lv.z + tv.w * lv.w;
        }
        out[(size_t)b * N_DIM + n] = acc;
    }
}

// ---------------------------------------------------------------------------
extern "C" void kernel_launch(void* const* d_in, const int* in_sizes, int n_in,
                              void* d_out, int out_size, void* d_ws, size_t ws_size,
                              hipStream_t stream) {
    const float* x         = (const float*)d_in[0];
    const int*   q_w       = (const int*)d_in[1];
    const float* wscales   = (const float*)d_in[2];
    const float* lora_down = (const float*)d_in[3];
    const float* lora_up   = (const float*)d_in[4];
    const float* smooth    = (const float*)d_in[5];
    const float* bias      = (const float*)d_in[6];
    float* out = (float*)d_out;

    char*  xq     = (char*)d_ws;                            // 256 KB
    float* ascale = (float*)((char*)d_ws + 262144);         // 16 KB
    float* t      = (float*)((char*)d_ws + 262144 + 16384); // 8 KB

    hipMemsetAsync(t, 0, B_DIM * R_DIM * sizeof(float), stream);
    quant_kernel<<<B_DIM * 16, 256, 0, stream>>>(x, smooth, xq, ascale);
    lora_down_kernel<<<B_DIM * 16, 256, 0, stream>>>(x, smooth, lora_down, t);
    main_kernel<<<N_DIM / 16, 256, 0, stream>>>(q_w, wscales, xq, ascale,
                                                t, lora_up, bias, out);
}